// Round 15
// baseline (141.296 us; speedup 1.0000x reference)
//
#include <hip/hip_runtime.h>

// Dilated attention, [1, 8192, 8, 64] fp32 in/out.
// Group 0 (heads 0-3): 4 segments x 2048 tokens, rate 1, dense causal.
// Group 1 (heads 4-7): 1 segment, odd tokens only (4096 dilated), evens = 0.
//
// prep:    gather dilated tokens -> bf16 ws (chunk-XOR-swizzled rows):
//            Kb[region][pos][64d], Vt[region][kb][64d][64key]
// attn:    64-query blocks, 4 waves split Q. S^T=mfma(K,Q) -> P^T via 4
//          ds_write_b64; O^T=mfma(V,P^T); in-lane l + 2 end shuffles.
//          K/V double-buffered LDS via global_load_lds, 1 barrier/iter.
//          R15: EVERY tile split into ceil(nkb/16) equal chunks (<=16 iters)
//          -> 1408 blocks, longest first, 1024 resident + 384 refill ->
//          resident waves stay ~16/CU (R14: unequal block lengths decayed
//          occupancy to 7.4 waves avg). Split tiles -> bf16 O-partial + fp32
//          l slots in ws (bf16 halves slot footprint to fit ws).
// combine: 448 blocks: sum 2-4 slots, normalize, store (+zero g1 evens).
// R5 lesson:  launch_bounds(256,8) -> VGPR spill catastrophe; keep (256,2).
// R6 lesson:  per-wave global frag reads = 805 MB L2/L3 traffic; stage in LDS.
// R7 lesson:  unswizzled ws rows -> 1.34e7 LDS conflict cycles; keep swizzle.
// R9 lesson:  LDS 40960 = exactly 4 blocks/CU.
// R10 lesson: fatter blocks at fewer blocks/CU regress; keep 64-q blocks.
// R12 lesson: fused atomic combine regressed 2x; keep combine as own launch.

#define LP 72

typedef __attribute__((ext_vector_type(8))) short bf16x8;
typedef __attribute__((ext_vector_type(4))) float f32x4;
typedef const unsigned int __attribute__((address_space(1)))* gp1;
typedef unsigned int __attribute__((address_space(3)))* lp3;

__device__ __forceinline__ unsigned short f2bf(float f) {
  unsigned u = __builtin_bit_cast(unsigned, f);
  u += 0x7fff + ((u >> 16) & 1);   // RNE
  return (unsigned short)(u >> 16);
}

__device__ __forceinline__ float bf2f(unsigned short u) {
  return __builtin_bit_cast(float, ((unsigned)u) << 16);
}

__device__ __forceinline__ int region_base(int head) {
  return (head < 4) ? head * 524288 : 2097152 + (head - 4) * 262144;
}

__device__ __forceinline__ void gl_lds16(const unsigned short* g, unsigned short* l) {
  __builtin_amdgcn_global_load_lds((gp1)g, (lp3)l, 16, 0, 0);
}

// slot offset within a head's g1 slot block for tile t (t>=16)
__device__ __forceinline__ int g1_slot_off(int t) {
  return (t < 32) ? 2 * (t - 16) : ((t < 48) ? 32 + 3 * (t - 32) : 80 + 4 * (t - 48));
}

__global__ __launch_bounds__(256, 4)
void prep_kernel(const float* __restrict__ K, const float* __restrict__ V,
                 unsigned short* __restrict__ Kb, unsigned short* __restrict__ Vt) {
  __shared__ unsigned short sT[64][LP];
  const int bid = blockIdx.x;
  int head, pos0, rate, off;
  if (bid < 512) { head = bid >> 7; pos0 = (bid & 127) * 64; rate = 1; off = 0; }
  else { int b = bid - 512; head = 4 + (b >> 6); pos0 = (b & 63) * 64; rate = 2; off = 1; }
  const int rb = region_base(head);
  const int tid = threadIdx.x;
  const int row = tid >> 2, dg = tid & 3;
  const long tok = (long)(pos0 + row) * rate + off;

  {
    const float* kp = K + tok * 512 + head * 64 + dg * 16;
    unsigned short tmp[16];
    #pragma unroll
    for (int i = 0; i < 4; ++i) {
      float4 f = ((const float4*)kp)[i];
      tmp[i * 4 + 0] = f2bf(f.x); tmp[i * 4 + 1] = f2bf(f.y);
      tmp[i * 4 + 2] = f2bf(f.z); tmp[i * 4 + 3] = f2bf(f.w);
    }
    const int s = row & 7;
    unsigned short* dstrow = Kb + rb + (long)(pos0 + row) * 64;
    *(int4*)(dstrow + (((2 * dg)     ^ s) * 8)) = ((int4*)tmp)[0];
    *(int4*)(dstrow + (((2 * dg + 1) ^ s) * 8)) = ((int4*)tmp)[1];
  }

  {
    const float* vp = V + tok * 512 + head * 64 + dg * 16;
    #pragma unroll
    for (int i = 0; i < 4; ++i) {
      float4 f = ((const float4*)vp)[i];
      unsigned* p = (unsigned*)&sT[row][dg * 16 + i * 4];
      p[0] = (unsigned)f2bf(f.x) | ((unsigned)f2bf(f.y) << 16);
      p[1] = (unsigned)f2bf(f.z) | ((unsigned)f2bf(f.w) << 16);
    }
  }
  __syncthreads();

  {
    const int wv = tid >> 6, lane = tid & 63;
    unsigned pk[8];
    #pragma unroll
    for (int j = 0; j < 8; ++j) {
      unsigned lo = sT[wv * 16 + 2 * j][lane];
      unsigned hi = sT[wv * 16 + 2 * j + 1][lane];
      pk[j] = lo | (hi << 16);
    }
    const int s = lane & 7;
    unsigned short* dstrow = Vt + rb + (long)pos0 * 64 + lane * 64;
    int4 a = {(int)pk[0], (int)pk[1], (int)pk[2], (int)pk[3]};
    int4 b = {(int)pk[4], (int)pk[5], (int)pk[6], (int)pk[7]};
    *(int4*)(dstrow + (((2 * wv)     ^ s) * 8)) = a;
    *(int4*)(dstrow + (((2 * wv + 1) ^ s) * 8)) = b;
  }
}

__global__ __launch_bounds__(256, 2)
void attn_kernel(const float* __restrict__ Q, const unsigned short* __restrict__ Kb,
                 const unsigned short* __restrict__ Vt, const int* __restrict__ IC,
                 float* __restrict__ O, char* __restrict__ SlotsB) {
  __shared__ __attribute__((aligned(16))) unsigned short sK[2][4096];  // [buf][64key][64d] swz
  __shared__ __attribute__((aligned(16))) unsigned short sV[2][4096];  // [buf][64d][64key] swz
  __shared__ __attribute__((aligned(16))) unsigned short sP[4][1024];  // [wave][16q][64k] swz

  const bool causal = (*IC) != 0;
  const int bid = blockIdx.x;
  int head, q0, seg0, rate, off, grp, nkb, nch, j, slot;
  if (bid < 640) {                       // group 1 chunks, longest tiles first
    int h = bid & 3;
    int m = 159 - (bid >> 2);            // 0..159, decode (t, j)
    int t;
    if (m < 16)      { t = m; j = 0; }
    else if (m < 48) { int r = m - 16; t = 16 + (r >> 1); j = r & 1; }
    else if (m < 96) { int r = m - 48; t = 32 + r / 3;    j = r % 3; }
    else             { int r = m - 96; t = 48 + (r >> 2); j = r & 3; }
    head = 4 + h; seg0 = 0; rate = 2; off = 1; grp = 1;
    q0 = t * 64;
    nkb = causal ? t + 1 : 64;
    nch = (t >> 4) + 1;
    slot = (nch > 1) ? (h * 144 + g1_slot_off(t) + j) : -1;
  } else {                               // group 0 chunks, longest first
    int b2 = bid - 640;
    int J = b2 & 15;
    int m = 47 - (b2 >> 4);              // 0..47, decode (u, j)
    int u;
    if (m < 16) { u = m; j = 0; }
    else        { int r = m - 16; u = 16 + (r >> 1); j = r & 1; }
    head = J & 3; seg0 = (J >> 2) * 2048; rate = 1; off = 0; grp = 0;
    q0 = seg0 + u * 64;
    nkb = causal ? u + 1 : 32;
    nch = (u >> 4) + 1;
    slot = (nch > 1) ? (576 + J * 32 + 2 * (u - 16) + j) : -1;
  }
  const int rb = region_base(head);
  const int tid = threadIdx.x, wave = tid >> 6, lane = tid & 63;
  const int l16 = lane & 15, quad = lane >> 4;
  const int ch0 = ((quad ^ (l16 & 7)) * 8);   // swizzled chunk offsets (shorts)
  const int ch1 = ch0 ^ 32;

  const int qloc = q0 - seg0;
  const int diagkb = qloc >> 6;
  const int klo = j * nkb / nch;
  const int khi = (j + 1) * nkb / nch;
  if (klo >= khi) return;

  // ---- Q B-frags (n=l16=this wave's query, k-dim=d); scale = log2(e)/8 ----
  const float QSCALE = 0.18033688011112042f;
  bf16x8 bQ[2];
  {
    long tok = (long)(q0 + wave * 16 + l16) * rate + off;
    const float* qp = Q + tok * 512 + head * 64 + quad * 8;
    #pragma unroll
    for (int kc = 0; kc < 2; ++kc) {
      float4 f0 = ((const float4*)(qp + kc * 32))[0];
      float4 f1 = ((const float4*)(qp + kc * 32))[1];
      bf16x8 a;
      a[0] = (short)f2bf(f0.x * QSCALE); a[1] = (short)f2bf(f0.y * QSCALE);
      a[2] = (short)f2bf(f0.z * QSCALE); a[3] = (short)f2bf(f0.w * QSCALE);
      a[4] = (short)f2bf(f1.x * QSCALE); a[5] = (short)f2bf(f1.y * QSCALE);
      a[6] = (short)f2bf(f1.z * QSCALE); a[7] = (short)f2bf(f1.w * QSCALE);
      bQ[kc] = a;
    }
  }

  f32x4 oacc[4];        // O^T: oacc[dt][r] = O[d=dt*16+quad*4+r][q=l16]
  float lsum = 0.f;
  #pragma unroll
  for (int dt = 0; dt < 4; ++dt) oacc[dt] = (f32x4){0.f, 0.f, 0.f, 0.f};

  unsigned short* myP = &sP[wave][0];
  const unsigned short* Ksrc = Kb + rb + (long)seg0 * 64;
  const unsigned short* Vsrc = Vt + rb + (long)seg0 * 64;

  const int o0 = wave * 1024;          // shorts
  const int lo = lane * 8;             // 16 B per lane
  {
    const unsigned short* kt = Ksrc + (long)klo * 4096;
    const unsigned short* vt = Vsrc + (long)klo * 4096;
    gl_lds16(kt + o0 + lo,       &sK[0][o0]);
    gl_lds16(kt + o0 + 512 + lo, &sK[0][o0 + 512]);
    gl_lds16(vt + o0 + lo,       &sV[0][o0]);
    gl_lds16(vt + o0 + 512 + lo, &sV[0][o0 + 512]);
  }

  for (int kb = klo; kb < khi; ++kb) {
    const int cur = (kb - klo) & 1;
    __syncthreads();   // vmcnt drain: buf[cur] staged; buf[cur^1] free
    if (kb + 1 < khi) {
      const unsigned short* kt = Ksrc + (long)(kb + 1) * 4096;
      const unsigned short* vt = Vsrc + (long)(kb + 1) * 4096;
      gl_lds16(kt + o0 + lo,       &sK[cur ^ 1][o0]);
      gl_lds16(kt + o0 + 512 + lo, &sK[cur ^ 1][o0 + 512]);
      gl_lds16(vt + o0 + lo,       &sV[cur ^ 1][o0]);
      gl_lds16(vt + o0 + 512 + lo, &sV[cur ^ 1][o0 + 512]);
    }
    const unsigned short* kbuf = &sK[cur][0];
    const unsigned short* vbuf = &sV[cur][0];

    // ---- S^T = K Q^T : col(l16)=query, row(quad*4+r)=key c*16+quad*4+r ----
    f32x4 sc[4];
    #pragma unroll
    for (int c = 0; c < 4; ++c) {
      const unsigned short* krow = &kbuf[(c * 16 + l16) * 64];
      bf16x8 a0 = *(const bf16x8*)(krow + ch0);
      bf16x8 a1 = *(const bf16x8*)(krow + ch1);
      f32x4 z = (f32x4){0.f, 0.f, 0.f, 0.f};
      z = __builtin_amdgcn_mfma_f32_16x16x32_bf16(a0, bQ[0], z, 0, 0, 0);
      z = __builtin_amdgcn_mfma_f32_16x16x32_bf16(a1, bQ[1], z, 0, 0, 0);
      sc[c] = z;
    }

    // ---- P^T = exp2(S^T), mask, in-lane l, 4 b64 swizzled LDS writes ----
    const bool needMask = causal && (kb == diagkb);
    const int myq = qloc + wave * 16 + l16;
    const int sw = l16 & 7;
    #pragma unroll
    for (int c = 0; c < 4; ++c) {
      unsigned short pb[4];
      #pragma unroll
      for (int r = 0; r < 4; ++r) {
        float e = __builtin_amdgcn_exp2f(sc[c][r]);
        if (needMask && (kb * 64 + c * 16 + quad * 4 + r > myq)) e = 0.f;
        lsum += e;
        pb[r] = f2bf(e);
      }
      unsigned w0 = (unsigned)pb[0] | ((unsigned)pb[1] << 16);
      unsigned w1 = (unsigned)pb[2] | ((unsigned)pb[3] << 16);
      const int wch = (c * 2 + (quad >> 1)) ^ sw;
      *(uint2*)&myP[l16 * 64 + wch * 8 + (quad & 1) * 4] = (uint2){w0, w1};
    }
    bf16x8 bP0 = *(const bf16x8*)&myP[l16 * 64 + ((quad ^ sw) << 3)];
    bf16x8 bP1 = *(const bf16x8*)&myP[l16 * 64 + (((4 + quad) ^ sw) << 3)];

    // ---- O^T += V^T P^T ----
    #pragma unroll
    for (int dt = 0; dt < 4; ++dt) {
      const unsigned short* vrow = &vbuf[(dt * 16 + l16) * 64];
      bf16x8 v0 = *(const bf16x8*)(vrow + ch0);
      bf16x8 v1 = *(const bf16x8*)(vrow + ch1);
      oacc[dt] = __builtin_amdgcn_mfma_f32_16x16x32_bf16(v0, bP0, oacc[dt], 0, 0, 0);
      oacc[dt] = __builtin_amdgcn_mfma_f32_16x16x32_bf16(v1, bP1, oacc[dt], 0, 0, 0);
    }
  }

  // ---- finish l ----
  lsum += __shfl_xor(lsum, 16);
  lsum += __shfl_xor(lsum, 32);

  const int row = wave * 16 + l16;     // query within the 64-q tile

  if (slot >= 0) {
    // ---- bf16 partial to slot: [q][d] + fp32 l at +8192 ----
    unsigned short* Sp = (unsigned short*)(SlotsB + (long)slot * 8448);
    #pragma unroll
    for (int dt = 0; dt < 4; ++dt) {
      ushort4 pk = {f2bf(oacc[dt][0]), f2bf(oacc[dt][1]),
                    f2bf(oacc[dt][2]), f2bf(oacc[dt][3])};
      *(ushort4*)&Sp[row * 64 + dt * 16 + quad * 4] = pk;
    }
    if (quad == 0)
      ((float*)(SlotsB + (long)slot * 8448 + 8192))[row] = lsum;
  } else {
    // ---- direct epilogue ----
    long tok = (long)(q0 + row) * rate + off;
    float inv = 1.0f / lsum;
    float* dst = O + tok * 512 + head * 64 + quad * 4;
    #pragma unroll
    for (int dt = 0; dt < 4; ++dt) {
      float4 v = {oacc[dt][0] * inv, oacc[dt][1] * inv,
                  oacc[dt][2] * inv, oacc[dt][3] * inv};
      *(float4*)(dst + dt * 16) = v;
    }
    if (grp == 1) {
      // zero paired even tokens (unsplit g1 tiles only)
      int p = q0 + (tid >> 2);
      int dd = (tid & 3) * 16;
      float4 z4 = {0.f, 0.f, 0.f, 0.f};
      float4* dste = (float4*)(O + (long)(2 * p) * 512 + head * 64 + dd);
      dste[0] = z4; dste[1] = z4; dste[2] = z4; dste[3] = z4;
    }
  }
}

__global__ __launch_bounds__(256, 4)
void combine_kernel(const char* __restrict__ SlotsB, const int* __restrict__ IC,
                    float* __restrict__ O) {
  const int b = blockIdx.x;            // 192 g1 split tiles + 256 g0 split tiles
  const int tid = threadIdx.x;
  const int row = tid >> 2, d0 = (tid & 3) * 16;
  int head, nch, slotbase, q0, rate, offt;
  bool evens;
  if (b < 192) {
    int h = b / 48, t = 16 + (b % 48);
    nch = (t >> 4) + 1;
    slotbase = h * 144 + g1_slot_off(t);
    head = 4 + h; q0 = t * 64; rate = 2; offt = 1; evens = true;
  } else {
    int b2 = b - 192;
    int J = b2 >> 4, u = 16 + (b2 & 15);
    nch = 2;
    slotbase = 576 + J * 32 + 2 * (u - 16);
    head = J & 3; q0 = (J >> 2) * 2048 + u * 64; rate = 1; offt = 0; evens = false;
  }

  float acc[16];
  #pragma unroll
  for (int i = 0; i < 16; ++i) acc[i] = 0.f;
  float l = 0.f;
  for (int c = 0; c < nch; ++c) {
    const unsigned short* Sp = (const unsigned short*)(SlotsB + (long)(slotbase + c) * 8448);
    #pragma unroll
    for (int k = 0; k < 4; ++k) {
      ushort4 v = *(const ushort4*)&Sp[row * 64 + d0 + k * 4];
      acc[k * 4 + 0] += bf2f(v.x); acc[k * 4 + 1] += bf2f(v.y);
      acc[k * 4 + 2] += bf2f(v.z); acc[k * 4 + 3] += bf2f(v.w);
    }
    l += ((const float*)(SlotsB + (long)(slotbase + c) * 8448 + 8192))[row];
  }
  const float inv = 1.0f / l;
  const long tok = (long)(q0 + row) * rate + offt;
  float* dst = O + tok * 512 + head * 64 + d0;
  #pragma unroll
  for (int k = 0; k < 4; ++k) {
    float4 o = {acc[k * 4 + 0] * inv, acc[k * 4 + 1] * inv,
                acc[k * 4 + 2] * inv, acc[k * 4 + 3] * inv};
    ((float4*)dst)[k] = o;
  }
  if (evens) {
    float* dste = O + (tok - 1) * 512 + head * 64 + d0;
    const float4 z = {0.f, 0.f, 0.f, 0.f};
    #pragma unroll
    for (int k = 0; k < 4; ++k) ((float4*)dste)[k] = z;
  }
}

extern "C" void kernel_launch(void* const* d_in, const int* in_sizes, int n_in,
                              void* d_out, int out_size, void* d_ws, size_t ws_size,
                              hipStream_t stream) {
  const float* q = (const float*)d_in[0];
  const float* k = (const float*)d_in[1];
  const float* v = (const float*)d_in[2];
  const int* ic = (const int*)d_in[3];
  unsigned short* Kb = (unsigned short*)d_ws;                 // 6 MB
  unsigned short* Vt = Kb + 3145728;                          // 6 MB
  char* SlotsB = (char*)d_ws + 12582912;                      // 1088 x 8448 B = 9.19 MB
  prep_kernel<<<dim3(768), dim3(256), 0, stream>>>(k, v, Kb, Vt);
  attn_kernel<<<dim3(1408), dim3(256), 0, stream>>>(q, Kb, Vt, ic, (float*)d_out, SlotsB);
  combine_kernel<<<dim3(448), dim3(256), 0, stream>>>(SlotsB, ic, (float*)d_out);
}